// Round 2
// baseline (247.544 us; speedup 1.0000x reference)
//
#include <hip/hip_runtime.h>

typedef unsigned short u16;
typedef __bf16 bf16x8 __attribute__((ext_vector_type(8)));
typedef float f32x4 __attribute__((ext_vector_type(4)));

// ---- fp32 -> bf16 (RNE) ----
__device__ inline u16 f2bf(float f) {
  union { float f; unsigned u; } a; a.f = f;
  unsigned u = a.u;
  return (u16)((u + 0x7fffu + ((u >> 16) & 1u)) >> 16);
}

__device__ inline void store_c(float* p, float v) { *p = v; }
__device__ inline void store_c(u16* p, float v) { *p = f2bf(v); }

// ---- elementwise fp32 -> bf16 convert, 4 elems/thread ----
__global__ __launch_bounds__(256) void cvt_kernel(const float* __restrict__ in,
                                                  u16* __restrict__ out) {
  size_t i = ((size_t)blockIdx.x * 256 + threadIdx.x) * 4;
  float4 v = *(const float4*)(in + i);
  ushort4 o;
  o.x = f2bf(v.x); o.y = f2bf(v.y); o.z = f2bf(v.z); o.w = f2bf(v.w);
  *(ushort4*)(out + i) = o;
}

// ============================================================================
// 256x256 8-wave GEMM core: C = A @ B^T, bf16 in, fp32 acc.
//   A: [M,K] rm (pre-offset to tile row 0), B: [N,K] rm (pre-offset), both lda/ldb elems.
//   BK=64 per K-tile, nt K-tiles. 512 threads = 8 waves (2M x 4N), wave tile 128x64.
//   LDS 128KB: A[2][256][64] @ 0, B[2][256][64] @ 32768 (u16 idx).
//   T2: XOR swizzle slot^=(row&7) on 16B slots — applied to BOTH the staged global
//       source (inverse) and the ds_read address (rule #21).
//   T4: counted vmcnt(8) — next tile's 8 loads/thread stay in flight across compute.
//   T5: setprio(1) around each 16-MFMA quadrant phase.
// ============================================================================
template <typename CT>
__device__ __forceinline__ void gemm_core(
    const u16* __restrict__ A, const u16* __restrict__ B, CT* __restrict__ C,
    int nt, int lda, int ldb, int ldc, int m0, int n0) {
  __shared__ __align__(16) u16 lds[65536];

  const int tid = threadIdx.x;
  const int ln = tid & 63, wv = tid >> 6;
  const int wr = wv >> 2, wc = wv & 3;  // 2 x 4 wave grid

  // stage one K-tile (BK=64): 4 A-chunks + 4 B-chunks of 16B per thread.
  // LDS dest is linear (chunk c at byte c*16); global source column is
  // inverse-swizzled so that swizzled reads see logical data (involution).
  auto stage = [&](int t, int buf) {
    const u16* Asrc = A + (size_t)t * 64;
    const u16* Bsrc = B + (size_t)t * 64;
#pragma unroll
    for (int i = 0; i < 4; ++i) {
      const int c = i * 512 + tid;          // 0..2047, 16B chunks; row = c>>3 (128B/row)
      const int row = c >> 3, slot = c & 7;
      const int col16 = slot ^ (row & 7);   // inverse swizzle on source
      __builtin_amdgcn_global_load_lds(
          (const __attribute__((address_space(1))) void*)(Asrc + (size_t)row * lda + col16 * 8),
          (__attribute__((address_space(3))) void*)(&lds[buf * 16384 + c * 8]), 16, 0, 0);
    }
#pragma unroll
    for (int i = 0; i < 4; ++i) {
      const int c = i * 512 + tid;
      const int row = c >> 3, slot = c & 7;
      const int col16 = slot ^ (row & 7);
      __builtin_amdgcn_global_load_lds(
          (const __attribute__((address_space(1))) void*)(Bsrc + (size_t)row * ldb + col16 * 8),
          (__attribute__((address_space(3))) void*)(&lds[32768 + buf * 16384 + c * 8]), 16, 0, 0);
    }
  };

  f32x4 acc[8][4] = {};

  stage(0, 0);
  for (int t = 0; t < nt; ++t) {
    const int cur = t & 1;
    // issue next tile into the OTHER buffer: its previous contents (tile t-1)
    // were fully read before tile t-1's closing barrier -> safe.
    if (t + 1 < nt) {
      stage(t + 1, cur ^ 1);
      asm volatile("s_waitcnt vmcnt(8)");   // tile t landed; t+1's 8 stay in flight
    } else {
      asm volatile("s_waitcnt vmcnt(0)");
    }
    __syncthreads();

    const u16* __restrict__ La = &lds[cur * 16384];
    const u16* __restrict__ Lb = &lds[32768 + cur * 16384];

    bf16x8 bfr[4][2];
#pragma unroll
    for (int q = 0; q < 4; ++q) {           // 4 quadrant phases, 16 MFMA each
      if (q == 0) {
#pragma unroll
        for (int ni = 0; ni < 4; ++ni)
#pragma unroll
          for (int ks = 0; ks < 2; ++ks) {
            const int row = wc * 64 + ni * 16 + (ln & 15);
            const int kc = ks * 4 + (ln >> 4);
            bfr[ni][ks] = *(const bf16x8*)&Lb[row * 64 + ((kc ^ (row & 7)) << 3)];
          }
      }
      bf16x8 afr[2][2];
#pragma unroll
      for (int mi = 0; mi < 2; ++mi)
#pragma unroll
        for (int ks = 0; ks < 2; ++ks) {
          const int row = wr * 128 + (q * 2 + mi) * 16 + (ln & 15);
          const int kc = ks * 4 + (ln >> 4);
          afr[mi][ks] = *(const bf16x8*)&La[row * 64 + ((kc ^ (row & 7)) << 3)];
        }
      __syncthreads();
      __builtin_amdgcn_s_setprio(1);
#pragma unroll
      for (int mi = 0; mi < 2; ++mi)
#pragma unroll
        for (int ni = 0; ni < 4; ++ni)
#pragma unroll
          for (int ks = 0; ks < 2; ++ks)
            acc[q * 2 + mi][ni] = __builtin_amdgcn_mfma_f32_16x16x32_bf16(
                afr[mi][ks], bfr[ni][ks], acc[q * 2 + mi][ni], 0, 0, 0);
      __builtin_amdgcn_s_setprio(0);
      __syncthreads();
    }
  }

  // epilogue: D col = lane&15 (n), row = (lane>>4)*4 + reg (m) — m89-verified
#pragma unroll
  for (int mi = 0; mi < 8; ++mi) {
    const int rbase = m0 + wr * 128 + mi * 16 + (ln >> 4) * 4;
#pragma unroll
    for (int ni = 0; ni < 4; ++ni) {
      const int col = n0 + wc * 64 + ni * 16 + (ln & 15);
#pragma unroll
      for (int r = 0; r < 4; ++r)
        store_c(&C[(size_t)(rbase + r) * ldc + col], acc[mi][ni][r]);
    }
  }
}

// ---- fused projections: Q = x Wq^T, K = x Wk^T, VT_b = Wv x_b^T (one dispatch) ----
__global__ __launch_bounds__(512, 2) void proj_kernel(
    const u16* __restrict__ xb, const u16* __restrict__ wqb,
    const u16* __restrict__ wkb, const u16* __restrict__ wvb,
    u16* __restrict__ Qb, u16* __restrict__ Kb, u16* __restrict__ VTb) {
  const int bid = blockIdx.x;
  const u16 *A, *B;
  u16* C;
  int ldc, m0, n0;
  if (bid < 256) {                 // Q (0..127) / K (128..255): M=8192, N=1024
    const int w = bid >> 7, r = bid & 127;
    m0 = (r >> 2) * 256; n0 = (r & 3) * 256;
    A = xb; B = w ? wkb : wqb; C = w ? Kb : Qb; ldc = 1024;
  } else {                         // VT per batch: M=1024, N=2048
    int r = bid - 256;
    const int z = r >> 5; r &= 31;
    m0 = (r >> 3) * 256; n0 = (r & 7) * 256;
    A = wvb; B = xb + (size_t)z * 2048 * 1024; C = VTb + (size_t)z * 1024 * 2048;
    ldc = 2048;
  }
  gemm_core<u16>(A + (size_t)m0 * 1024, B + (size_t)n0 * 1024, C, 16, 1024, 1024, ldc, m0, n0);
}

// ---- S_b = Q_b K_b^T (fp32 out), skip fully-masked upper tiles ----
__global__ __launch_bounds__(512, 2) void qkt_kernel(
    const u16* __restrict__ Qb, const u16* __restrict__ Kb, float* __restrict__ Sb) {
  const int m0 = blockIdx.y * 256, n0 = blockIdx.x * 256;
  if (n0 > m0) return;
  const u16* A = Qb + (size_t)blockIdx.z * 2048 * 1024 + (size_t)m0 * 1024;
  const u16* B = Kb + (size_t)blockIdx.z * 2048 * 1024 + (size_t)n0 * 1024;
  float* C = Sb + (size_t)blockIdx.z * 2048 * 2048;
  gemm_core<float>(A, B, C, 16, 1024, 1024, 2048, m0, n0);
}

// ---- O_b = P_b VT_b^T (fp32 out), K limited to causal extent m0+256 ----
__global__ __launch_bounds__(512, 2) void pv_kernel(
    const u16* __restrict__ P, const u16* __restrict__ VTb, float* __restrict__ out) {
  const int m0 = blockIdx.y * 256, n0 = blockIdx.x * 256;
  const u16* A = P + (size_t)blockIdx.z * 2048 * 4096 + (size_t)m0 * 4096;  // P row stride 4096 u16
  const u16* B = VTb + (size_t)blockIdx.z * 1024 * 2048 + (size_t)n0 * 2048;
  float* C = out + (size_t)blockIdx.z * 2048 * 1024;
  gemm_core<float>(A, B, C, m0 / 64 + 4, 4096, 2048, 1024, m0, n0);
}

// ---- causal row softmax on fp32 scores, writes bf16 P in-place (row stride 4096 u16) ----
__global__ __launch_bounds__(256) void softmax_kernel(float* __restrict__ S, float scale) {
  const int q = blockIdx.x;
  float* row = S + ((size_t)blockIdx.y * 2048 + q) * 2048;
  const int t = threadIdx.x;
  float4 v0 = *(const float4*)(row + t * 4);
  float4 v1 = *(const float4*)(row + 1024 + t * 4);
  float x[8] = {v0.x, v0.y, v0.z, v0.w, v1.x, v1.y, v1.z, v1.w};
  float m = -3.4e38f;
#pragma unroll
  for (int i = 0; i < 8; ++i) {
    const int j = (i < 4) ? (t * 4 + i) : (1024 + t * 4 + (i - 4));
    x[i] = (j <= q) ? x[i] * scale : -3.4e38f;  // mask BEFORE use (upper region holds garbage)
    m = fmaxf(m, x[i]);
  }
#pragma unroll
  for (int off = 32; off > 0; off >>= 1) m = fmaxf(m, __shfl_xor(m, off, 64));
  __shared__ float redm[4], reds[4];
  const int ln = t & 63, wv = t >> 6;
  if (ln == 0) redm[wv] = m;
  __syncthreads();
  m = fmaxf(fmaxf(redm[0], redm[1]), fmaxf(redm[2], redm[3]));

  float p[8];
  float s = 0.f;
#pragma unroll
  for (int i = 0; i < 8; ++i) {
    p[i] = __expf(x[i] - m);
    s += p[i];
  }
#pragma unroll
  for (int off = 32; off > 0; off >>= 1) s += __shfl_xor(s, off, 64);
  if (ln == 0) reds[wv] = s;
  __syncthreads();
  s = reds[0] + reds[1] + reds[2] + reds[3];
  const float r = 1.0f / s;

  u16* prow = (u16*)row;
  ushort4 o0, o1;
  o0.x = f2bf(p[0] * r); o0.y = f2bf(p[1] * r); o0.z = f2bf(p[2] * r); o0.w = f2bf(p[3] * r);
  o1.x = f2bf(p[4] * r); o1.y = f2bf(p[5] * r); o1.z = f2bf(p[6] * r); o1.w = f2bf(p[7] * r);
  *(ushort4*)(prow + t * 4) = o0;
  *(ushort4*)(prow + 1024 + t * 4) = o1;
}

extern "C" void kernel_launch(void* const* d_in, const int* in_sizes, int n_in,
                              void* d_out, int out_size, void* d_ws, size_t ws_size,
                              hipStream_t stream) {
  const float* x  = (const float*)d_in[0];
  const float* Wq = (const float*)d_in[1];
  const float* Wk = (const float*)d_in[2];
  const float* Wv = (const float*)d_in[3];
  float* out = (float*)d_out;

  char* ws = (char*)d_ws;
  u16* xb   = (u16*)(ws);                        // 16 MB  x bf16 [8192][1024]
  u16* wqb  = (u16*)(ws + (16ul << 20));         //  2 MB
  u16* wkb  = (u16*)(ws + (18ul << 20));         //  2 MB
  u16* wvb  = (u16*)(ws + (20ul << 20));         //  2 MB
  u16* Qb   = (u16*)(ws + (22ul << 20));         // 16 MB  Q bf16 [4][2048][1024]
  u16* Kb   = (u16*)(ws + (38ul << 20));         // 16 MB  K bf16
  u16* VTb  = (u16*)(ws + (54ul << 20));         // 16 MB  V^T bf16 [4][1024][2048]
  float* Sb = (float*)(ws + (70ul << 20));       // 64 MB  scores fp32 (P bf16 in-place)

  cvt_kernel<<<8192, 256, 0, stream>>>(x, xb);
  cvt_kernel<<<1024, 256, 0, stream>>>(Wq, wqb);
  cvt_kernel<<<1024, 256, 0, stream>>>(Wk, wkb);
  cvt_kernel<<<1024, 256, 0, stream>>>(Wv, wvb);

  // Q, K, VT in one 384-block dispatch
  proj_kernel<<<384, 512, 0, stream>>>(xb, wqb, wkb, wvb, Qb, Kb, VTb);

  // S = Q K^T (causal-skipped tiles)
  qkt_kernel<<<dim3(8, 8, 4), 512, 0, stream>>>(Qb, Kb, Sb);

  // softmax (scale = 1/sqrt(1024)), P bf16 in-place
  softmax_kernel<<<dim3(2048, 4, 1), 256, 0, stream>>>(Sb, 0.03125f);

  // O = P VT^T, causal K-limit
  pv_kernel<<<dim3(4, 8, 4), 512, 0, stream>>>((const u16*)Sb, VTb, out);
}

// Round 3
// 175.563 us; speedup vs baseline: 1.4100x; 1.4100x over previous
//
#include <hip/hip_runtime.h>

typedef unsigned short u16;
typedef __bf16 bf16x8 __attribute__((ext_vector_type(8)));
typedef float f32x4 __attribute__((ext_vector_type(4)));

#define AS1 __attribute__((address_space(1)))
#define AS3 __attribute__((address_space(3)))

// ---- fp32 -> bf16 (RNE) ----
__device__ inline u16 f2bf(float f) {
  union { float f; unsigned u; } a; a.f = f;
  unsigned u = a.u;
  return (u16)((u + 0x7fffu + ((u >> 16) & 1u)) >> 16);
}

// ---- elementwise fp32 -> bf16 convert, 4 elems/thread ----
__global__ __launch_bounds__(256) void cvt_kernel(const float* __restrict__ in,
                                                  u16* __restrict__ out) {
  size_t i = ((size_t)blockIdx.x * 256 + threadIdx.x) * 4;
  float4 v = *(const float4*)(in + i);
  ushort4 o;
  o.x = f2bf(v.x); o.y = f2bf(v.y); o.z = f2bf(v.z); o.w = f2bf(v.w);
  *(ushort4*)(out + i) = o;
}

// three weight matrices in one dispatch (1024 blocks each)
__global__ __launch_bounds__(256) void cvt3_kernel(
    const float* __restrict__ a, const float* __restrict__ b, const float* __restrict__ c,
    u16* __restrict__ oa, u16* __restrict__ ob, u16* __restrict__ oc) {
  int bid = blockIdx.x;
  const float* in; u16* out;
  if (bid < 1024) { in = a; out = oa; }
  else if (bid < 2048) { in = b; out = ob; bid -= 1024; }
  else { in = c; out = oc; bid -= 2048; }
  size_t i = ((size_t)bid * 256 + threadIdx.x) * 4;
  float4 v = *(const float4*)(in + i);
  ushort4 o;
  o.x = f2bf(v.x); o.y = f2bf(v.y); o.z = f2bf(v.z); o.w = f2bf(v.w);
  *(ushort4*)(out + i) = o;
}

// ============================================================================
// 256x256 8-wave GEMM core, m201-style 4-phase schedule: C = A @ B^T.
//   512 threads = 8 waves (2M x 4N), wave tile 128x64, BK=64, nt K-tiles (nt>=4).
//   LDS 128KB: A[2][256][64] @ 0, B[2][256][64] @ 32768 (u16 idx).
//   RAW s_barrier only (no __syncthreads -> no vmcnt(0) drain).
//   Dead-region staging: during tile t (buf p): ph0/1 stage A(t+1)->buf p^1
//   (A[p^1] dead since tile t-1 end); ph2/3 stage B(t+2)->buf p (B[p] dead
//   after ph0: ALL B-frags consumed by ph0's MFMAs). One vmcnt(4)/tile.
//   T2 swizzle: 16B slot ^= (row&7) on both staged source and ds_read.
// ============================================================================
template <typename CT>
__device__ __forceinline__ void gemm_core(
    const u16* __restrict__ A, const u16* __restrict__ B, CT* __restrict__ C,
    int nt, int lda, int ldb, int ldc, int m0, int n0, bool atom) {
  __shared__ __align__(16) u16 lds[65536];

  const int tid = threadIdx.x;
  const int ln = tid & 63, wv = tid >> 6;
  const int wr = wv >> 2, wc = wv & 3;  // 2 x 4 wave grid

  // stage one 128-row half-tile (2 x 16B chunks/thread); LDS dest linear,
  // global source column inverse-swizzled (involution).
  auto stage = [&](const u16* src, int ld, int t, int h, int ldsbase) {
#pragma unroll
    for (int i = 0; i < 2; ++i) {
      const int c = h * 1024 + i * 512 + tid;    // 16B chunk id; row = c>>3
      const int row = c >> 3, slot = c & 7;
      const int col = (slot ^ (row & 7)) * 8;    // elements
      __builtin_amdgcn_global_load_lds(
          (const AS1 void*)(src + (size_t)row * ld + (size_t)t * 64 + col),
          (AS3 void*)(&lds[ldsbase + c * 8]), 16, 0, 0);
    }
  };

  f32x4 acc[8][4] = {};

  // prologue: tiles 0 and 1 fully staged (16 loads/thread)
  stage(B, ldb, 0, 0, 32768); stage(B, ldb, 0, 1, 32768);
  stage(A, lda, 0, 0, 0);     stage(A, lda, 0, 1, 0);
  if (nt > 1) {
    stage(B, ldb, 1, 0, 32768 + 16384); stage(B, ldb, 1, 1, 32768 + 16384);
    stage(A, lda, 1, 0, 16384);         stage(A, lda, 1, 1, 16384);
    asm volatile("s_waitcnt vmcnt(8)" ::: "memory");  // tile 0 landed; tile 1 in flight
  } else {
    asm volatile("s_waitcnt vmcnt(0)" ::: "memory");
  }
  __builtin_amdgcn_s_barrier();

  for (int t = 0; t < nt; ++t) {
    const int p = t & 1;
    const u16* La = &lds[p * 16384];
    const u16* Lb = &lds[32768 + p * 16384];
    bf16x8 bfr[4][2];
#pragma unroll
    for (int q = 0; q < 4; ++q) {
      if (q == 0) {
        // pin tile-boundary reads below the barrier that published tile t
        __builtin_amdgcn_sched_barrier(0);
#pragma unroll
        for (int ni = 0; ni < 4; ++ni)
#pragma unroll
          for (int ks = 0; ks < 2; ++ks) {
            const int row = wc * 64 + ni * 16 + (ln & 15);
            const int kc = ks * 4 + (ln >> 4);
            bfr[ni][ks] = *(const bf16x8*)&Lb[row * 64 + ((kc ^ (row & 7)) << 3)];
          }
      }
      bf16x8 afr[2][2];
#pragma unroll
      for (int mi = 0; mi < 2; ++mi)
#pragma unroll
        for (int ks = 0; ks < 2; ++ks) {
          const int row = wr * 128 + (q * 2 + mi) * 16 + (ln & 15);
          const int kc = ks * 4 + (ln >> 4);
          afr[mi][ks] = *(const bf16x8*)&La[row * 64 + ((kc ^ (row & 7)) << 3)];
        }
      // staging (tile 0 skips A(1): already staged in prologue)
      if (q == 0)      { if (t >= 1 && t + 1 < nt) stage(A, lda, t + 1, 0, (p ^ 1) * 16384); }
      else if (q == 1) { if (t >= 1 && t + 1 < nt) stage(A, lda, t + 1, 1, (p ^ 1) * 16384); }
      else if (q == 2) { if (t + 2 < nt) stage(B, ldb, t + 2, 0, 32768 + p * 16384); }
      else             { if (t + 2 < nt) stage(B, ldb, t + 2, 1, 32768 + p * 16384); }

      __builtin_amdgcn_s_barrier();
      __builtin_amdgcn_s_setprio(1);
#pragma unroll
      for (int mi = 0; mi < 2; ++mi)
#pragma unroll
        for (int ni = 0; ni < 4; ++ni)
#pragma unroll
          for (int ks = 0; ks < 2; ++ks)
            acc[q * 2 + mi][ni] = __builtin_amdgcn_mfma_f32_16x16x32_bf16(
                afr[mi][ks], bfr[ni][ks], acc[q * 2 + mi][ni], 0, 0, 0);
      __builtin_amdgcn_s_setprio(0);
      if (q == 3) {
        if (t + 2 < nt)      asm volatile("s_waitcnt vmcnt(4)" ::: "memory");  // A(t+1) landed, B(t+2) flying
        else if (t + 1 < nt) asm volatile("s_waitcnt vmcnt(0)" ::: "memory");  // final boundary
      }
      __builtin_amdgcn_s_barrier();
    }
  }

  // epilogue: D col = lane&15 (n), row = (lane>>4)*4 + reg (m) — m89-verified
#pragma unroll
  for (int mi = 0; mi < 8; ++mi) {
    const int rbase = m0 + wr * 128 + mi * 16 + (ln >> 4) * 4;
#pragma unroll
    for (int ni = 0; ni < 4; ++ni) {
      const int col = n0 + wc * 64 + ni * 16 + (ln & 15);
#pragma unroll
      for (int r = 0; r < 4; ++r) {
        const float v = acc[mi][ni][r];
        CT* ptr = &C[(size_t)(rbase + r) * ldc + col];
        if constexpr (sizeof(CT) == 4) {
          if (atom) atomicAdd((float*)ptr, v);
          else *(float*)ptr = v;
        } else {
          *ptr = f2bf(v);
        }
      }
    }
  }
}

// ---- fused projections: Q = x Wq^T, K = x Wk^T, VT_b = Wv x_b^T ----
__global__ __launch_bounds__(512, 2) void proj_kernel(
    const u16* __restrict__ xb, const u16* __restrict__ wqb,
    const u16* __restrict__ wkb, const u16* __restrict__ wvb,
    u16* __restrict__ Qb, u16* __restrict__ Kb, u16* __restrict__ VTb) {
  const int bid = blockIdx.x;
  const u16 *A, *B;
  u16* C;
  int ldc, m0, n0;
  if (bid < 256) {                 // Q (0..127) / K (128..255): M=8192, N=1024
    const int w = bid >> 7, r = bid & 127;
    m0 = (r >> 2) * 256; n0 = (r & 3) * 256;
    A = xb; B = w ? wkb : wqb; C = w ? Kb : Qb; ldc = 1024;
  } else {                         // VT per batch: M=1024, N=2048
    int r = bid - 256;
    const int z = r >> 5; r &= 31;
    m0 = (r >> 3) * 256; n0 = (r & 7) * 256;
    A = wvb; B = xb + (size_t)z * 2048 * 1024; C = VTb + (size_t)z * 1024 * 2048;
    ldc = 2048;
  }
  gemm_core<u16>(A + (size_t)m0 * 1024, B + (size_t)n0 * 1024, C, 16, 1024, 1024, ldc, m0, n0, false);
}

// ---- S_b = Q_b K_b^T (fp32), only the 36 lower-triangle tiles per batch ----
__global__ __launch_bounds__(512, 2) void qkt_kernel(
    const u16* __restrict__ Qb, const u16* __restrict__ Kb, float* __restrict__ Sb) {
  const int x = blockIdx.x;  // 0..35 triangular index
  int mi = 0;
  while ((mi + 1) * (mi + 2) / 2 <= x) ++mi;
  const int ni = x - mi * (mi + 1) / 2;
  const int m0 = mi * 256, n0 = ni * 256;
  const u16* A = Qb + (size_t)blockIdx.y * 2048 * 1024 + (size_t)m0 * 1024;
  const u16* B = Kb + (size_t)blockIdx.y * 2048 * 1024 + (size_t)n0 * 1024;
  float* C = Sb + (size_t)blockIdx.y * 2048 * 2048;
  gemm_core<float>(A, B, C, 16, 1024, 1024, 2048, m0, n0, false);
}

// ---- O_b = P_b VT_b^T (fp32), K split for balance; split chunks atomicAdd ----
__global__ __launch_bounds__(512, 2) void pv_kernel(
    const u16* __restrict__ P, const u16* __restrict__ VTb, float* __restrict__ out) {
  const int c = blockIdx.x;  // 0..11
  int m, k0, ntc; bool atom;
  if (c < 4) { m = c; k0 = 0; ntc = 4 * (c + 1); atom = false; }       // nt 4,8,12,16
  else {
    const int j = c - 4;
    m = 4 + (j >> 1);
    const int nth = 2 * (m + 1);   // 10,12,14,16 (half of 20,24,28,32)
    k0 = (j & 1) * nth; ntc = nth; atom = true;
  }
  const int m0 = m * 256, n0 = blockIdx.y * 256;
  const u16* A = P + (size_t)blockIdx.z * 2048 * 4096 + (size_t)m0 * 4096 + (size_t)k0 * 64;
  const u16* B = VTb + (size_t)blockIdx.z * 1024 * 2048 + (size_t)n0 * 2048 + (size_t)k0 * 64;
  float* C = out + (size_t)blockIdx.z * 2048 * 1024;
  gemm_core<float>(A, B, C, ntc, 4096, 2048, 1024, m0, n0, atom);
}

// ---- causal row softmax on fp32 scores, writes bf16 P in-place (row stride 4096 u16) ----
__global__ __launch_bounds__(256) void softmax_kernel(float* __restrict__ S, float scale) {
  const int q = blockIdx.x;
  float* row = S + ((size_t)blockIdx.y * 2048 + q) * 2048;
  const int t = threadIdx.x;
  float4 v0 = *(const float4*)(row + t * 4);
  float4 v1 = *(const float4*)(row + 1024 + t * 4);
  float x[8] = {v0.x, v0.y, v0.z, v0.w, v1.x, v1.y, v1.z, v1.w};
  float m = -3.4e38f;
#pragma unroll
  for (int i = 0; i < 8; ++i) {
    const int j = (i < 4) ? (t * 4 + i) : (1024 + t * 4 + (i - 4));
    x[i] = (j <= q) ? x[i] * scale : -3.4e38f;  // mask BEFORE use (upper region garbage)
    m = fmaxf(m, x[i]);
  }
#pragma unroll
  for (int off = 32; off > 0; off >>= 1) m = fmaxf(m, __shfl_xor(m, off, 64));
  __shared__ float redm[4], reds[4];
  const int ln = t & 63, wv = t >> 6;
  if (ln == 0) redm[wv] = m;
  __syncthreads();
  m = fmaxf(fmaxf(redm[0], redm[1]), fmaxf(redm[2], redm[3]));

  float p[8];
  float s = 0.f;
#pragma unroll
  for (int i = 0; i < 8; ++i) {
    p[i] = __expf(x[i] - m);
    s += p[i];
  }
#pragma unroll
  for (int off = 32; off > 0; off >>= 1) s += __shfl_xor(s, off, 64);
  if (ln == 0) reds[wv] = s;
  __syncthreads();
  s = reds[0] + reds[1] + reds[2] + reds[3];
  const float r = 1.0f / s;

  u16* prow = (u16*)row;
  ushort4 o0, o1;
  o0.x = f2bf(p[0] * r); o0.y = f2bf(p[1] * r); o0.z = f2bf(p[2] * r); o0.w = f2bf(p[3] * r);
  o1.x = f2bf(p[4] * r); o1.y = f2bf(p[5] * r); o1.z = f2bf(p[6] * r); o1.w = f2bf(p[7] * r);
  *(ushort4*)(prow + t * 4) = o0;
  *(ushort4*)(prow + 1024 + t * 4) = o1;
}

extern "C" void kernel_launch(void* const* d_in, const int* in_sizes, int n_in,
                              void* d_out, int out_size, void* d_ws, size_t ws_size,
                              hipStream_t stream) {
  const float* x  = (const float*)d_in[0];
  const float* Wq = (const float*)d_in[1];
  const float* Wk = (const float*)d_in[2];
  const float* Wv = (const float*)d_in[3];
  float* out = (float*)d_out;

  char* ws = (char*)d_ws;
  u16* xb   = (u16*)(ws);                        // 16 MB  x bf16 [8192][1024]
  u16* wqb  = (u16*)(ws + (16ul << 20));         //  2 MB
  u16* wkb  = (u16*)(ws + (18ul << 20));         //  2 MB
  u16* wvb  = (u16*)(ws + (20ul << 20));         //  2 MB
  u16* Qb   = (u16*)(ws + (22ul << 20));         // 16 MB  Q bf16 [4][2048][1024]
  u16* Kb   = (u16*)(ws + (38ul << 20));         // 16 MB  K bf16
  u16* VTb  = (u16*)(ws + (54ul << 20));         // 16 MB  V^T bf16 [4][1024][2048]
  float* Sb = (float*)(ws + (70ul << 20));       // 64 MB  scores fp32 (P bf16 in-place)

  hipMemsetAsync(out, 0, (size_t)out_size * 4, stream);  // base for pv atomics

  cvt_kernel<<<8192, 256, 0, stream>>>(x, xb);
  cvt3_kernel<<<3072, 256, 0, stream>>>(Wq, Wk, Wv, wqb, wkb, wvb);

  proj_kernel<<<384, 512, 0, stream>>>(xb, wqb, wkb, wvb, Qb, Kb, VTb);

  qkt_kernel<<<dim3(36, 4), 512, 0, stream>>>(Qb, Kb, Sb);

  softmax_kernel<<<dim3(2048, 4), 256, 0, stream>>>(Sb, 0.03125f);

  pv_kernel<<<dim3(12, 4, 4), 512, 0, stream>>>((const u16*)Sb, VTb, out);
}

// Round 4
// 173.381 us; speedup vs baseline: 1.4277x; 1.0126x over previous
//
#include <hip/hip_runtime.h>

typedef unsigned short u16;
typedef __bf16 bf16x8 __attribute__((ext_vector_type(8)));
typedef float f32x4 __attribute__((ext_vector_type(4)));

#define AS1 __attribute__((address_space(1)))
#define AS3 __attribute__((address_space(3)))

// ---- fp32 -> bf16 (RNE) ----
__device__ inline u16 f2bf(float f) {
  union { float f; unsigned u; } a; a.f = f;
  unsigned u = a.u;
  return (u16)((u + 0x7fffu + ((u >> 16) & 1u)) >> 16);
}

// ---- elementwise fp32 -> bf16 convert, 4 elems/thread ----
__global__ __launch_bounds__(256) void cvt_kernel(const float* __restrict__ in,
                                                  u16* __restrict__ out) {
  size_t i = ((size_t)blockIdx.x * 256 + threadIdx.x) * 4;
  float4 v = *(const float4*)(in + i);
  ushort4 o;
  o.x = f2bf(v.x); o.y = f2bf(v.y); o.z = f2bf(v.z); o.w = f2bf(v.w);
  *(ushort4*)(out + i) = o;
}

// three weight matrices in one dispatch (1024 blocks each)
__global__ __launch_bounds__(256) void cvt3_kernel(
    const float* __restrict__ a, const float* __restrict__ b, const float* __restrict__ c,
    u16* __restrict__ oa, u16* __restrict__ ob, u16* __restrict__ oc) {
  int bid = blockIdx.x;
  const float* in; u16* out;
  if (bid < 1024) { in = a; out = oa; }
  else if (bid < 2048) { in = b; out = ob; bid -= 1024; }
  else { in = c; out = oc; bid -= 2048; }
  size_t i = ((size_t)bid * 256 + threadIdx.x) * 4;
  float4 v = *(const float4*)(in + i);
  ushort4 o;
  o.x = f2bf(v.x); o.y = f2bf(v.y); o.z = f2bf(v.z); o.w = f2bf(v.w);
  *(ushort4*)(out + i) = o;
}

// ============================================================================
// BMx256 8-wave GEMM core, 4-phase dead-region schedule: C = A @ B^T.
//   BM=256: wave tile 128x64, LDS 128KB, 2 m-frags/phase  (proj_qk, qkt, pv)
//   BM=128: wave tile  64x64, LDS  96KB, 1 m-frag /phase  (vt)
//   RAW s_barrier only; one counted vmcnt(4) per K-tile (never drains queue).
//   Staging: ph0(/ph1) stage A(t+1)->buf p^1; ph2/ph3 stage B(t+2)->buf p
//   (B[p] dead after ph0's reads, which completed before ph1's barrier).
//   T2 swizzle: 16B slot ^= (row&7) on both staged source and ds_read.
// ============================================================================
template <typename CT, int BM>
__device__ __forceinline__ void gemm_core(
    const u16* __restrict__ A, const u16* __restrict__ B, CT* __restrict__ C,
    int nt, int lda, int ldb, int ldc, int m0, int n0, bool atom) {
  constexpr int ABUF = BM * 64;     // u16 per A buffer
  constexpr int ASW = BM / 64;      // A staging sweeps per tile (4 or 2)
  constexpr int PH_MI = BM / 128;   // m-frags per phase (2 or 1)
  __shared__ __align__(16) u16 lds[2 * ABUF + 32768];

  const int tid = threadIdx.x;
  const int ln = tid & 63, wv = tid >> 6;
  const int wr = wv >> 2, wc = wv & 3;  // 2 x 4 wave grid

  // stage 64 rows (512 x 16B chunks, 1/thread); LDS dest linear, global source
  // column inverse-swizzled (involution).
  auto sweep = [&](const u16* src, int ld, int t, int s, int base) {
    const int c = s * 512 + tid;
    const int row = c >> 3, slot = c & 7;
    const int col = (slot ^ (row & 7)) * 8;
    __builtin_amdgcn_global_load_lds(
        (const AS1 void*)(src + (size_t)row * ld + (size_t)t * 64 + col),
        (AS3 void*)(&lds[base + c * 8]), 16, 0, 0);
  };

  f32x4 acc[2 * BM / 64][4] = {};

  // prologue: tiles 0 and 1 fully staged
#pragma unroll
  for (int s = 0; s < 4; ++s) sweep(B, ldb, 0, s, 2 * ABUF);
#pragma unroll
  for (int s = 0; s < ASW; ++s) sweep(A, lda, 0, s, 0);
  if (nt > 1) {
#pragma unroll
    for (int s = 0; s < 4; ++s) sweep(B, ldb, 1, s, 2 * ABUF + 16384);
#pragma unroll
    for (int s = 0; s < ASW; ++s) sweep(A, lda, 1, s, ABUF);
    if constexpr (ASW == 4) asm volatile("s_waitcnt vmcnt(8)" ::: "memory");
    else                    asm volatile("s_waitcnt vmcnt(6)" ::: "memory");
  } else {
    asm volatile("s_waitcnt vmcnt(0)" ::: "memory");
  }
  __builtin_amdgcn_s_barrier();

  for (int t = 0; t < nt; ++t) {
    const int p = t & 1;
    const u16* La = &lds[p * ABUF];
    const u16* Lb = &lds[2 * ABUF + p * 16384];
    bf16x8 bfr[4][2];
#pragma unroll
    for (int q = 0; q < 4; ++q) {
      if (q == 0) {
        // pin tile-boundary reads below the barrier that published tile t
        __builtin_amdgcn_sched_barrier(0);
#pragma unroll
        for (int ni = 0; ni < 4; ++ni)
#pragma unroll
          for (int ks = 0; ks < 2; ++ks) {
            const int row = wc * 64 + ni * 16 + (ln & 15);
            const int kc = ks * 4 + (ln >> 4);
            bfr[ni][ks] = *(const bf16x8*)&Lb[row * 64 + ((kc ^ (row & 7)) << 3)];
          }
      }
      bf16x8 afr[PH_MI][2];
#pragma unroll
      for (int mi = 0; mi < PH_MI; ++mi)
#pragma unroll
        for (int ks = 0; ks < 2; ++ks) {
          const int row = wr * (BM / 2) + (q * PH_MI + mi) * 16 + (ln & 15);
          const int kc = ks * 4 + (ln >> 4);
          afr[mi][ks] = *(const bf16x8*)&La[row * 64 + ((kc ^ (row & 7)) << 3)];
        }
      // dead-region staging (tile 0 skips A(1): staged in prologue)
      if constexpr (PH_MI == 2) {
        if (q == 0)      { if (t >= 1 && t + 1 < nt) { sweep(A, lda, t + 1, 0, (p ^ 1) * ABUF); sweep(A, lda, t + 1, 1, (p ^ 1) * ABUF); } }
        else if (q == 1) { if (t >= 1 && t + 1 < nt) { sweep(A, lda, t + 1, 2, (p ^ 1) * ABUF); sweep(A, lda, t + 1, 3, (p ^ 1) * ABUF); } }
        else if (q == 2) { if (t + 2 < nt) { sweep(B, ldb, t + 2, 0, 2 * ABUF + p * 16384); sweep(B, ldb, t + 2, 1, 2 * ABUF + p * 16384); } }
        else             { if (t + 2 < nt) { sweep(B, ldb, t + 2, 2, 2 * ABUF + p * 16384); sweep(B, ldb, t + 2, 3, 2 * ABUF + p * 16384); } }
      } else {
        if (q == 0)      { if (t >= 1 && t + 1 < nt) { sweep(A, lda, t + 1, 0, (p ^ 1) * ABUF); sweep(A, lda, t + 1, 1, (p ^ 1) * ABUF); } }
        else if (q == 2) { if (t + 2 < nt) { sweep(B, ldb, t + 2, 0, 2 * ABUF + p * 16384); sweep(B, ldb, t + 2, 1, 2 * ABUF + p * 16384); } }
        else if (q == 3) { if (t + 2 < nt) { sweep(B, ldb, t + 2, 2, 2 * ABUF + p * 16384); sweep(B, ldb, t + 2, 3, 2 * ABUF + p * 16384); } }
      }

      __builtin_amdgcn_s_barrier();
      __builtin_amdgcn_s_setprio(1);
#pragma unroll
      for (int mi = 0; mi < PH_MI; ++mi)
#pragma unroll
        for (int ni = 0; ni < 4; ++ni)
#pragma unroll
          for (int ks = 0; ks < 2; ++ks)
            acc[q * PH_MI + mi][ni] = __builtin_amdgcn_mfma_f32_16x16x32_bf16(
                afr[mi][ks], bfr[ni][ks], acc[q * PH_MI + mi][ni], 0, 0, 0);
      __builtin_amdgcn_s_setprio(0);
      if (q == 3) {
        if (t + 2 < nt)      asm volatile("s_waitcnt vmcnt(4)" ::: "memory");  // A(t+1) landed, B(t+2) flying
        else if (t + 1 < nt) asm volatile("s_waitcnt vmcnt(0)" ::: "memory");  // final boundary
      }
      __builtin_amdgcn_s_barrier();
    }
  }

  // epilogue: D col = lane&15 (n), row = (lane>>4)*4 + reg (m) — m89-verified
#pragma unroll
  for (int mi = 0; mi < 2 * BM / 64; ++mi) {
    const int rbase = m0 + wr * (BM / 2) + mi * 16 + (ln >> 4) * 4;
#pragma unroll
    for (int ni = 0; ni < 4; ++ni) {
      const int col = n0 + wc * 64 + ni * 16 + (ln & 15);
#pragma unroll
      for (int r = 0; r < 4; ++r) {
        const float v = acc[mi][ni][r];
        CT* ptr = &C[(size_t)(rbase + r) * ldc + col];
        if constexpr (sizeof(CT) == 4) {
          if (atom) atomicAdd((float*)ptr, v);
          else *(float*)ptr = v;
        } else {
          *ptr = f2bf(v);
        }
      }
    }
  }
}

// ---- Q = x Wq^T, K = x Wk^T: 256 blocks of 256x256 (exactly 1 round) ----
__global__ __launch_bounds__(512, 2) void proj_qk_kernel(
    const u16* __restrict__ xb, const u16* __restrict__ wqb,
    const u16* __restrict__ wkb, u16* __restrict__ Qb, u16* __restrict__ Kb) {
  const int bid = blockIdx.x;
  const int w = bid >> 7, r = bid & 127;
  const int m0 = (r >> 2) * 256, n0 = (r & 3) * 256;
  const u16* B = w ? wkb : wqb;
  u16* C = w ? Kb : Qb;
  gemm_core<u16, 256>(xb + (size_t)m0 * 1024, B + (size_t)n0 * 1024, C,
                      16, 1024, 1024, 1024, m0, n0, false);
}

// ---- VT_b = Wv x_b^T: 256 blocks of 128x256 (exactly 1 round) ----
__global__ __launch_bounds__(512, 2) void vt_kernel(
    const u16* __restrict__ wvb, const u16* __restrict__ xb, u16* __restrict__ VTb) {
  const int z = blockIdx.x >> 6, r = blockIdx.x & 63;
  const int m0 = (r >> 3) * 128, n0 = (r & 7) * 256;
  gemm_core<u16, 128>(wvb + (size_t)m0 * 1024,
                      xb + (size_t)z * 2048 * 1024 + (size_t)n0 * 1024,
                      VTb + (size_t)z * 1024 * 2048,
                      16, 1024, 1024, 2048, m0, n0, false);
}

// ---- S_b = Q_b K_b^T (fp32), only the 36 lower-triangle tiles per batch ----
__global__ __launch_bounds__(512, 2) void qkt_kernel(
    const u16* __restrict__ Qb, const u16* __restrict__ Kb, float* __restrict__ Sb) {
  const int x = blockIdx.x;  // 0..35 triangular index
  int mi = 0;
  while ((mi + 1) * (mi + 2) / 2 <= x) ++mi;
  const int ni = x - mi * (mi + 1) / 2;
  const int m0 = mi * 256, n0 = ni * 256;
  const u16* A = Qb + (size_t)blockIdx.y * 2048 * 1024 + (size_t)m0 * 1024;
  const u16* B = Kb + (size_t)blockIdx.y * 2048 * 1024 + (size_t)n0 * 1024;
  float* C = Sb + (size_t)blockIdx.y * 2048 * 2048;
  gemm_core<float, 256>(A, B, C, 16, 1024, 1024, 2048, m0, n0, false);
}

// ---- O_b = P_b VT_b^T (fp32), K split for balance; split chunks atomicAdd ----
__global__ __launch_bounds__(512, 2) void pv_kernel(
    const u16* __restrict__ P, const u16* __restrict__ VTb, float* __restrict__ out) {
  const int c = blockIdx.x;  // 0..11
  int m, k0, ntc; bool atom;
  if (c < 4) { m = c; k0 = 0; ntc = 4 * (c + 1); atom = false; }       // nt 4,8,12,16
  else {
    const int j = c - 4;
    m = 4 + (j >> 1);
    const int nth = 2 * (m + 1);   // 10,12,14,16 (half of 20,24,28,32)
    k0 = (j & 1) * nth; ntc = nth; atom = true;
  }
  const int m0 = m * 256, n0 = blockIdx.y * 256;
  const u16* A = P + (size_t)blockIdx.z * 2048 * 4096 + (size_t)m0 * 4096 + (size_t)k0 * 64;
  const u16* B = VTb + (size_t)blockIdx.z * 1024 * 2048 + (size_t)n0 * 2048 + (size_t)k0 * 64;
  float* C = out + (size_t)blockIdx.z * 2048 * 1024;
  gemm_core<float, 256>(A, B, C, ntc, 4096, 2048, 1024, m0, n0, atom);
}

// ---- causal row softmax, bf16 P in-place (row stride 4096 u16).
//      Rows q<1024 skip cols 1024..2047 entirely (pv never reads them). ----
__global__ __launch_bounds__(256) void softmax_kernel(float* __restrict__ S, float scale) {
  const int q = blockIdx.x;
  const bool full = (q >= 1024);
  float* row = S + ((size_t)blockIdx.y * 2048 + q) * 2048;
  const int t = threadIdx.x;
  float4 v0 = *(const float4*)(row + t * 4);
  float4 v1 = full ? *(const float4*)(row + 1024 + t * 4) : float4{0, 0, 0, 0};
  float x[8] = {v0.x, v0.y, v0.z, v0.w, v1.x, v1.y, v1.z, v1.w};
  float m = -3.4e38f;
#pragma unroll
  for (int i = 0; i < 8; ++i) {
    const int j = (i < 4) ? (t * 4 + i) : (1024 + t * 4 + (i - 4));
    x[i] = (j <= q) ? x[i] * scale : -3.4e38f;  // mask BEFORE use (upper region garbage)
    m = fmaxf(m, x[i]);
  }
#pragma unroll
  for (int off = 32; off > 0; off >>= 1) m = fmaxf(m, __shfl_xor(m, off, 64));
  __shared__ float redm[4], reds[4];
  const int ln = t & 63, wv = t >> 6;
  if (ln == 0) redm[wv] = m;
  __syncthreads();
  m = fmaxf(fmaxf(redm[0], redm[1]), fmaxf(redm[2], redm[3]));

  float p[8];
  float s = 0.f;
#pragma unroll
  for (int i = 0; i < 8; ++i) {
    p[i] = __expf(x[i] - m);
    s += p[i];
  }
#pragma unroll
  for (int off = 32; off > 0; off >>= 1) s += __shfl_xor(s, off, 64);
  if (ln == 0) reds[wv] = s;
  __syncthreads();
  s = reds[0] + reds[1] + reds[2] + reds[3];
  const float r = 1.0f / s;

  u16* prow = (u16*)row;
  ushort4 o0, o1;
  o0.x = f2bf(p[0] * r); o0.y = f2bf(p[1] * r); o0.z = f2bf(p[2] * r); o0.w = f2bf(p[3] * r);
  *(ushort4*)(prow + t * 4) = o0;
  if (full) {
    o1.x = f2bf(p[4] * r); o1.y = f2bf(p[5] * r); o1.z = f2bf(p[6] * r); o1.w = f2bf(p[7] * r);
    *(ushort4*)(prow + 1024 + t * 4) = o1;
  }
}

extern "C" void kernel_launch(void* const* d_in, const int* in_sizes, int n_in,
                              void* d_out, int out_size, void* d_ws, size_t ws_size,
                              hipStream_t stream) {
  const float* x  = (const float*)d_in[0];
  const float* Wq = (const float*)d_in[1];
  const float* Wk = (const float*)d_in[2];
  const float* Wv = (const float*)d_in[3];
  float* out = (float*)d_out;

  char* ws = (char*)d_ws;
  u16* xb   = (u16*)(ws);                        // 16 MB  x bf16 [8192][1024]
  u16* wqb  = (u16*)(ws + (16ul << 20));         //  2 MB
  u16* wkb  = (u16*)(ws + (18ul << 20));         //  2 MB
  u16* wvb  = (u16*)(ws + (20ul << 20));         //  2 MB
  u16* Qb   = (u16*)(ws + (22ul << 20));         // 16 MB  Q bf16 [4][2048][1024]
  u16* Kb   = (u16*)(ws + (38ul << 20));         // 16 MB  K bf16
  u16* VTb  = (u16*)(ws + (54ul << 20));         // 16 MB  V^T bf16 [4][1024][2048]
  float* Sb = (float*)(ws + (70ul << 20));       // 64 MB  scores fp32 (P bf16 in-place)

  // zero only the atomic-target region of out (rows 1024..2047 per batch)
  for (int b = 0; b < 4; ++b)
    hipMemsetAsync(out + ((size_t)b * 2048 + 1024) * 1024, 0, 1024 * 1024 * 4, stream);

  cvt_kernel<<<8192, 256, 0, stream>>>(x, xb);
  cvt3_kernel<<<3072, 256, 0, stream>>>(Wq, Wk, Wv, wqb, wkb, wvb);

  proj_qk_kernel<<<256, 512, 0, stream>>>(xb, wqb, wkb, Qb, Kb);
  vt_kernel<<<256, 512, 0, stream>>>(wvb, xb, VTb);

  qkt_kernel<<<dim3(36, 4), 512, 0, stream>>>(Qb, Kb, Sb);

  softmax_kernel<<<dim3(2048, 4), 256, 0, stream>>>(Sb, 0.03125f);

  pv_kernel<<<dim3(12, 4, 4), 512, 0, stream>>>((const u16*)Sb, VTb, out);
}

// Round 5
// 158.692 us; speedup vs baseline: 1.5599x; 1.0926x over previous
//
#include <hip/hip_runtime.h>

typedef unsigned short u16;
typedef __bf16 bf16x8 __attribute__((ext_vector_type(8)));
typedef float f32x4 __attribute__((ext_vector_type(4)));

#define AS1 __attribute__((address_space(1)))
#define AS3 __attribute__((address_space(3)))

// ---- fp32 -> bf16 (RNE) ----
__device__ inline u16 f2bf(float f) {
  union { float f; unsigned u; } a; a.f = f;
  unsigned u = a.u;
  return (u16)((u + 0x7fffu + ((u >> 16) & 1u)) >> 16);
}

// ---- all fp32 -> bf16 converts in one dispatch ----
// blocks 0..8191: x (32MB); 8192..11263: Wq,Wk,Wv (1024 each)
__global__ __launch_bounds__(256) void cvt_all_kernel(
    const float* __restrict__ x, const float* __restrict__ wq,
    const float* __restrict__ wk, const float* __restrict__ wv,
    u16* __restrict__ xb, u16* __restrict__ wqb,
    u16* __restrict__ wkb, u16* __restrict__ wvb) {
  int bid = blockIdx.x;
  const float* in; u16* out;
  if (bid < 8192) { in = x; out = xb; }
  else if (bid < 9216) { in = wq; out = wqb; bid -= 8192; }
  else if (bid < 10240) { in = wk; out = wkb; bid -= 9216; }
  else { in = wv; out = wvb; bid -= 10240; }
  size_t i = ((size_t)bid * 256 + threadIdx.x) * 4;
  float4 v = *(const float4*)(in + i);
  ushort4 o;
  o.x = f2bf(v.x); o.y = f2bf(v.y); o.z = f2bf(v.z); o.w = f2bf(v.w);
  *(ushort4*)(out + i) = o;
}

// ============================================================================
// BMx256 8-wave GEMM core, 4-phase dead-region schedule: C = A @ B^T.
//   BM=256: wave tile 128x64, 128KB of the passed LDS, 2 m-frags/phase
//   BM=128: wave tile  64x64,  96KB of the passed LDS, 1 m-frag /phase
//   RAW s_barrier only; one counted vmcnt(4) per K-tile (never drains queue).
//   Staging: ph0(/ph1) stage A(t+1)->buf p^1; ph2/ph3 stage B(t+2)->buf p.
//   T2 swizzle: 16B slot ^= (row&7) on both staged source and ds_read.
//   LDS is passed in (callers share one static 128KB array across branches).
// ============================================================================
template <typename CT, int BM>
__device__ __forceinline__ void gemm_core(
    u16* __restrict__ lds,
    const u16* __restrict__ A, const u16* __restrict__ B, CT* __restrict__ C,
    int nt, int lda, int ldb, int ldc, int m0, int n0) {
  constexpr int ABUF = BM * 64;     // u16 per A buffer
  constexpr int ASW = BM / 64;      // A staging sweeps per tile (4 or 2)
  constexpr int PH_MI = BM / 128;   // m-frags per phase (2 or 1)

  const int tid = threadIdx.x;
  const int ln = tid & 63, wv = tid >> 6;
  const int wr = wv >> 2, wc = wv & 3;  // 2 x 4 wave grid

  // stage 64 rows (512 x 16B chunks, 1/thread); LDS dest linear, global source
  // column inverse-swizzled (involution).
  auto sweep = [&](const u16* src, int ld, int t, int s, int base) {
    const int c = s * 512 + tid;
    const int row = c >> 3, slot = c & 7;
    const int col = (slot ^ (row & 7)) * 8;
    __builtin_amdgcn_global_load_lds(
        (const AS1 void*)(src + (size_t)row * ld + (size_t)t * 64 + col),
        (AS3 void*)(&lds[base + c * 8]), 16, 0, 0);
  };

  f32x4 acc[2 * BM / 64][4] = {};

  // prologue: tiles 0 and 1 fully staged
#pragma unroll
  for (int s = 0; s < 4; ++s) sweep(B, ldb, 0, s, 2 * ABUF);
#pragma unroll
  for (int s = 0; s < ASW; ++s) sweep(A, lda, 0, s, 0);
  if (nt > 1) {
#pragma unroll
    for (int s = 0; s < 4; ++s) sweep(B, ldb, 1, s, 2 * ABUF + 16384);
#pragma unroll
    for (int s = 0; s < ASW; ++s) sweep(A, lda, 1, s, ABUF);
    if constexpr (ASW == 4) asm volatile("s_waitcnt vmcnt(8)" ::: "memory");
    else                    asm volatile("s_waitcnt vmcnt(6)" ::: "memory");
  } else {
    asm volatile("s_waitcnt vmcnt(0)" ::: "memory");
  }
  __builtin_amdgcn_s_barrier();

  for (int t = 0; t < nt; ++t) {
    const int p = t & 1;
    const u16* La = &lds[p * ABUF];
    const u16* Lb = &lds[2 * ABUF + p * 16384];
    bf16x8 bfr[4][2];
#pragma unroll
    for (int q = 0; q < 4; ++q) {
      if (q == 0) {
        // pin tile-boundary reads below the barrier that published tile t
        __builtin_amdgcn_sched_barrier(0);
#pragma unroll
        for (int ni = 0; ni < 4; ++ni)
#pragma unroll
          for (int ks = 0; ks < 2; ++ks) {
            const int row = wc * 64 + ni * 16 + (ln & 15);
            const int kc = ks * 4 + (ln >> 4);
            bfr[ni][ks] = *(const bf16x8*)&Lb[row * 64 + ((kc ^ (row & 7)) << 3)];
          }
      }
      bf16x8 afr[PH_MI][2];
#pragma unroll
      for (int mi = 0; mi < PH_MI; ++mi)
#pragma unroll
        for (int ks = 0; ks < 2; ++ks) {
          const int row = wr * (BM / 2) + (q * PH_MI + mi) * 16 + (ln & 15);
          const int kc = ks * 4 + (ln >> 4);
          afr[mi][ks] = *(const bf16x8*)&La[row * 64 + ((kc ^ (row & 7)) << 3)];
        }
      // dead-region staging (tile 0 skips A(1): staged in prologue)
      if constexpr (PH_MI == 2) {
        if (q == 0)      { if (t >= 1 && t + 1 < nt) { sweep(A, lda, t + 1, 0, (p ^ 1) * ABUF); sweep(A, lda, t + 1, 1, (p ^ 1) * ABUF); } }
        else if (q == 1) { if (t >= 1 && t + 1 < nt) { sweep(A, lda, t + 1, 2, (p ^ 1) * ABUF); sweep(A, lda, t + 1, 3, (p ^ 1) * ABUF); } }
        else if (q == 2) { if (t + 2 < nt) { sweep(B, ldb, t + 2, 0, 2 * ABUF + p * 16384); sweep(B, ldb, t + 2, 1, 2 * ABUF + p * 16384); } }
        else             { if (t + 2 < nt) { sweep(B, ldb, t + 2, 2, 2 * ABUF + p * 16384); sweep(B, ldb, t + 2, 3, 2 * ABUF + p * 16384); } }
      } else {
        if (q == 0)      { if (t >= 1 && t + 1 < nt) { sweep(A, lda, t + 1, 0, (p ^ 1) * ABUF); sweep(A, lda, t + 1, 1, (p ^ 1) * ABUF); } }
        else if (q == 2) { if (t + 2 < nt) { sweep(B, ldb, t + 2, 0, 2 * ABUF + p * 16384); sweep(B, ldb, t + 2, 1, 2 * ABUF + p * 16384); } }
        else if (q == 3) { if (t + 2 < nt) { sweep(B, ldb, t + 2, 2, 2 * ABUF + p * 16384); sweep(B, ldb, t + 2, 3, 2 * ABUF + p * 16384); } }
      }

      __builtin_amdgcn_s_barrier();
      __builtin_amdgcn_s_setprio(1);
#pragma unroll
      for (int mi = 0; mi < PH_MI; ++mi)
#pragma unroll
        for (int ni = 0; ni < 4; ++ni)
#pragma unroll
          for (int ks = 0; ks < 2; ++ks)
            acc[q * PH_MI + mi][ni] = __builtin_amdgcn_mfma_f32_16x16x32_bf16(
                afr[mi][ks], bfr[ni][ks], acc[q * PH_MI + mi][ni], 0, 0, 0);
      __builtin_amdgcn_s_setprio(0);
      if (q == 3) {
        if (t + 2 < nt)      asm volatile("s_waitcnt vmcnt(4)" ::: "memory");  // A(t+1) landed, B(t+2) flying
        else if (t + 1 < nt) asm volatile("s_waitcnt vmcnt(0)" ::: "memory");  // final boundary
      }
      __builtin_amdgcn_s_barrier();
    }
  }

  // epilogue: D col = lane&15 (n), row = (lane>>4)*4 + reg (m) — m89-verified
#pragma unroll
  for (int mi = 0; mi < 2 * BM / 64; ++mi) {
    const int rbase = m0 + wr * (BM / 2) + mi * 16 + (ln >> 4) * 4;
#pragma unroll
    for (int ni = 0; ni < 4; ++ni) {
      const int col = n0 + wc * 64 + ni * 16 + (ln & 15);
#pragma unroll
      for (int r = 0; r < 4; ++r) {
        const float v = acc[mi][ni][r];
        CT* ptr = &C[(size_t)(rbase + r) * ldc + col];
        if constexpr (sizeof(CT) == 4) *(float*)ptr = v;
        else                           *ptr = f2bf(v);
      }
    }
  }
}

// ---- Q = x Wq^T, K = x Wk^T: 256 blocks of 256x256 (exactly 1 round) ----
__global__ __launch_bounds__(512, 2) void proj_qk_kernel(
    const u16* __restrict__ xb, const u16* __restrict__ wqb,
    const u16* __restrict__ wkb, u16* __restrict__ Qb, u16* __restrict__ Kb) {
  __shared__ __align__(16) u16 lds[65536];
  const int bid = blockIdx.x;
  const int w = bid >> 7, r = bid & 127;
  const int m0 = (r >> 2) * 256, n0 = (r & 3) * 256;
  const u16* B = w ? wkb : wqb;
  u16* C = w ? Kb : Qb;
  gemm_core<u16, 256>(lds, xb + (size_t)m0 * 1024, B + (size_t)n0 * 1024, C,
                      16, 1024, 1024, 1024, m0, n0);
}

// ---- merged: qkt (blocks 0..143, 36 lower-tri tiles x 4 batches)
//              + vt (blocks 144..399, VT_b = Wv x_b^T, 128x256 tiles) ----
__global__ __launch_bounds__(512, 2) void vtqkt_kernel(
    const u16* __restrict__ Qb, const u16* __restrict__ Kb, float* __restrict__ Sb,
    const u16* __restrict__ wvb, const u16* __restrict__ xb, u16* __restrict__ VTb) {
  __shared__ __align__(16) u16 lds[65536];
  const int bid = blockIdx.x;
  if (bid < 144) {   // qkt: long blocks first for backfill scheduling
    const int z = bid / 36, x = bid % 36;
    int mi = 0;
    while ((mi + 1) * (mi + 2) / 2 <= x) ++mi;
    const int ni = x - mi * (mi + 1) / 2;
    const int m0 = mi * 256, n0 = ni * 256;
    const u16* A = Qb + (size_t)z * 2048 * 1024 + (size_t)m0 * 1024;
    const u16* B = Kb + (size_t)z * 2048 * 1024 + (size_t)n0 * 1024;
    float* C = Sb + (size_t)z * 2048 * 2048;
    gemm_core<float, 256>(lds, A, B, C, 16, 1024, 1024, 2048, m0, n0);
  } else {           // vt
    int r = bid - 144;
    const int z = r >> 6; r &= 63;
    const int m0 = (r >> 3) * 128, n0 = (r & 7) * 256;
    gemm_core<u16, 128>(lds, wvb + (size_t)m0 * 1024,
                        xb + (size_t)z * 2048 * 1024 + (size_t)n0 * 1024,
                        VTb + (size_t)z * 1024 * 2048,
                        16, 1024, 1024, 2048, m0, n0);
  }
}

// pv chunk table: <=2 contributions per output tile, max 16 K-tiles per chunk.
// m-tile m has K-extent 4(m+1) tiles; m0..m2 single chunk -> out;
// m3..m7 split in half: chunk0 -> out (plain), chunk1 -> scratch (plain).
__constant__ signed char PVM[13] = {7, 7, 6, 6, 5, 5, 4, 4, 3, 3, 2, 1, 0};
__constant__ signed char PVK[13] = {0, 16, 0, 14, 0, 12, 0, 10, 0, 8, 0, 0, 0};
__constant__ signed char PVN[13] = {16, 16, 14, 14, 12, 12, 10, 10, 8, 8, 12, 8, 4};
__constant__ signed char PVS[13] = {0, 1, 0, 1, 0, 1, 0, 1, 0, 1, 0, 0, 0};

// ---- O_b = P_b VT_b^T (fp32); no atomics. scratch holds rows 768..2047/batch ----
__global__ __launch_bounds__(512, 2) void pv_kernel(
    const u16* __restrict__ P, const u16* __restrict__ VTb,
    float* __restrict__ out, float* __restrict__ scr) {
  __shared__ __align__(16) u16 lds[65536];
  const int c = blockIdx.x;
  const int m = PVM[c], k0 = PVK[c], ntc = PVN[c];
  const int m0 = m * 256, n0 = blockIdx.y * 256;
  const size_t z = blockIdx.z;
  const u16* A = P + z * 2048 * 4096 + (size_t)m0 * 4096 + (size_t)k0 * 64;
  const u16* B = VTb + z * 1024 * 2048 + (size_t)n0 * 2048 + (size_t)k0 * 64;
  // scratch layout [z][row-768][1024]: pass base shifted so row indexing works
  float* C = PVS[c] ? (scr + z * 1280 * 1024 - (size_t)768 * 1024)
                    : (out + z * 2048 * 1024);
  gemm_core<float, 256>(lds, A, B, C, ntc, 4096, 2048, 1024, m0, n0);
}

// ---- out[rows 768..2047 per batch] += scratch ----
__global__ __launch_bounds__(256) void reduce_kernel(float* __restrict__ out,
                                                     const float* __restrict__ scr) {
  const size_t i = ((size_t)blockIdx.x * 256 + threadIdx.x) * 4;
  const size_t zsz = 1280 * 1024;
  const size_t z = i / zsz, rem = i - z * zsz;
  float4 a = *(const float4*)(scr + i);
  float4* o = (float4*)(out + z * 2048 * 1024 + (size_t)768 * 1024 + rem);
  float4 b = *o;
  b.x += a.x; b.y += a.y; b.z += a.z; b.w += a.w;
  *o = b;
}

// ---- causal row softmax, bf16 P in-place (row stride 4096 u16).
//      Rows q<1024 skip cols 1024..2047 entirely (pv never reads them). ----
__global__ __launch_bounds__(256) void softmax_kernel(float* __restrict__ S, float scale) {
  const int q = blockIdx.x;
  const bool full = (q >= 1024);
  float* row = S + ((size_t)blockIdx.y * 2048 + q) * 2048;
  const int t = threadIdx.x;
  float4 v0 = *(const float4*)(row + t * 4);
  float4 v1 = full ? *(const float4*)(row + 1024 + t * 4) : float4{0, 0, 0, 0};
  float x[8] = {v0.x, v0.y, v0.z, v0.w, v1.x, v1.y, v1.z, v1.w};
  float m = -3.4e38f;
#pragma unroll
  for (int i = 0; i < 8; ++i) {
    const int j = (i < 4) ? (t * 4 + i) : (1024 + t * 4 + (i - 4));
    x[i] = (j <= q) ? x[i] * scale : -3.4e38f;  // mask BEFORE use (upper region garbage)
    m = fmaxf(m, x[i]);
  }
#pragma unroll
  for (int off = 32; off > 0; off >>= 1) m = fmaxf(m, __shfl_xor(m, off, 64));
  __shared__ float redm[4], reds[4];
  const int ln = t & 63, wv = t >> 6;
  if (ln == 0) redm[wv] = m;
  __syncthreads();
  m = fmaxf(fmaxf(redm[0], redm[1]), fmaxf(redm[2], redm[3]));

  float p[8];
  float s = 0.f;
#pragma unroll
  for (int i = 0; i < 8; ++i) {
    p[i] = __expf(x[i] - m);
    s += p[i];
  }
#pragma unroll
  for (int off = 32; off > 0; off >>= 1) s += __shfl_xor(s, off, 64);
  if (ln == 0) reds[wv] = s;
  __syncthreads();
  s = reds[0] + reds[1] + reds[2] + reds[3];
  const float r = 1.0f / s;

  u16* prow = (u16*)row;
  ushort4 o0, o1;
  o0.x = f2bf(p[0] * r); o0.y = f2bf(p[1] * r); o0.z = f2bf(p[2] * r); o0.w = f2bf(p[3] * r);
  *(ushort4*)(prow + t * 4) = o0;
  if (full) {
    o1.x = f2bf(p[4] * r); o1.y = f2bf(p[5] * r); o1.z = f2bf(p[6] * r); o1.w = f2bf(p[7] * r);
    *(ushort4*)(prow + 1024 + t * 4) = o1;
  }
}

extern "C" void kernel_launch(void* const* d_in, const int* in_sizes, int n_in,
                              void* d_out, int out_size, void* d_ws, size_t ws_size,
                              hipStream_t stream) {
  const float* x  = (const float*)d_in[0];
  const float* Wq = (const float*)d_in[1];
  const float* Wk = (const float*)d_in[2];
  const float* Wv = (const float*)d_in[3];
  float* out = (float*)d_out;

  char* ws = (char*)d_ws;
  u16* xb   = (u16*)(ws);                        // 16 MB  x bf16 [8192][1024]
  u16* wqb  = (u16*)(ws + (16ul << 20));         //  2 MB
  u16* wkb  = (u16*)(ws + (18ul << 20));         //  2 MB
  u16* wvb  = (u16*)(ws + (20ul << 20));         //  2 MB
  u16* Qb   = (u16*)(ws + (22ul << 20));         // 16 MB  Q bf16 [4][2048][1024]
  u16* Kb   = (u16*)(ws + (38ul << 20));         // 16 MB  K bf16
  u16* VTb  = (u16*)(ws + (54ul << 20));         // 16 MB  V^T bf16 [4][1024][2048]
  float* Sb = (float*)(ws + (70ul << 20));       // 64 MB  scores fp32 (P bf16 in-place)
  // pv scratch (20 MB) aliases xb/wqb/wkb — dead after vtqkt, written by pv,
  // read by reduce: stream order makes this safe and replay-deterministic.
  float* Osc = (float*)(ws);

  cvt_all_kernel<<<11264, 256, 0, stream>>>(x, Wq, Wk, Wv, xb, wqb, wkb, wvb);

  proj_qk_kernel<<<256, 512, 0, stream>>>(xb, wqb, wkb, Qb, Kb);

  vtqkt_kernel<<<400, 512, 0, stream>>>(Qb, Kb, Sb, wvb, xb, VTb);

  softmax_kernel<<<dim3(2048, 4), 256, 0, stream>>>(Sb, 0.03125f);

  pv_kernel<<<dim3(13, 4, 4), 512, 0, stream>>>((const u16*)Sb, VTb, out, Osc);

  reduce_kernel<<<5120, 256, 0, stream>>>(out, Osc);
}